// Round 19
// baseline (26.137 us; speedup 1.0000x reference)
//
#include <hip/hip_runtime.h>
#include <math.h>

typedef unsigned long long ull;
typedef float vf4 __attribute__((ext_vector_type(4)));   // native vec for NT loads

#define S_GRID   112
#define BATCH_N  64
#define NBOX     100
#define SS       (S_GRID * S_GRID)       // 12544 cells per image
#define NCELLS   (BATCH_N * SS)          // 802816
#define NF4      (NCELLS * 5)            // 4,014,080 float4s in pred
#define CELLSZ   (1.0f / (float)S_GRID)
#define BLK      256
#define CH       7                       // float4 chunks per thread
#define SGRID_B  2240                    // 2240*256*7 == NF4 exactly (no tail)
#define HIT_BASE SGRID_B                 // hit blocks: 2240..2303
#define NPART    (SGRID_B + BATCH_N)     // 2304 partials
#define BREGION  (BLK * CH)              // 1792 float4s = 28KB contiguous per block

// ---------- device helpers ----------

__device__ __forceinline__ float iou_fn(float px, float py, float pw, float ph,
                                        float gx, float gy, float gw, float gh) {
    // matches reference _iou (eps = 1e-6)
    float px1 = px - pw * 0.5f, px2 = px + pw * 0.5f;
    float py1 = py - ph * 0.5f, py2 = py + ph * 0.5f;
    float gx1 = gx - gw * 0.5f, gx2 = gx + gw * 0.5f;
    float gy1 = gy - gh * 0.5f, gy2 = gy + gh * 0.5f;
    float iw = fmaxf(fminf(px2, gx2) - fmaxf(px1, gx1), 0.f);
    float ih = fmaxf(fminf(py2, gy2) - fmaxf(py1, gy1), 0.f);
    float inter = iw * ih;
    float ap = fmaxf(px2 - px1, 0.f) * fmaxf(py2 - py1, 0.f);
    float ag = fmaxf(gx2 - gx1, 0.f) * fmaxf(gy2 - gy1, 0.f);
    float uni = ap + ag - inter;
    return inter / (uni + 1e-6f);
}

__device__ __forceinline__ float ciou_fn(float px, float py, float pw, float ph,
                                         float gx, float gy, float gw, float gh) {
    // matches reference _ciou (eps = 1e-7)
    const float eps = 1e-7f;
    float px1 = px - pw * 0.5f, px2 = px + pw * 0.5f;
    float py1 = py - ph * 0.5f, py2 = py + ph * 0.5f;
    float gx1 = gx - gw * 0.5f, gx2 = gx + gw * 0.5f;
    float gy1 = gy - gh * 0.5f, gy2 = gy + gh * 0.5f;
    float iw = fmaxf(fminf(px2, gx2) - fmaxf(px1, gx1), 0.f);
    float ih = fmaxf(fminf(py2, gy2) - fmaxf(py1, gy1), 0.f);
    float inter = iw * ih;
    float ap = fmaxf(px2 - px1, 0.f) * fmaxf(py2 - py1, 0.f);
    float ag = fmaxf(gx2 - gx1, 0.f) * fmaxf(gy2 - gy1, 0.f);
    float uni = ap + ag - inter;
    float iou = inter / (uni + eps);
    float dx = px - gx, dy = py - gy;
    float rho2 = dx * dx + dy * dy;
    float cw = fmaxf(px2, gx2) - fminf(px1, gx1);
    float ch = fmaxf(py2, gy2) - fminf(py1, gy1);
    float c2 = cw * cw + ch * ch + eps;
    float dv = atanf(gw / (gh + eps)) - atanf(pw / (ph + eps));
    float v = 0.40528473456935109f * dv * dv;   // 4/pi^2
    float alpha = v / (1.f - iou + v + eps);
    return 1.f - iou + rho2 / c2 + alpha * v;
}

__device__ __forceinline__ float focal_fn(float logit, float t) {
    float bce = fmaxf(logit, 0.f) - logit * t + log1pf(expf(-fabsf(logit)));
    float p = 1.f / (1.f + expf(-logit));
    float p_t = t * p + (1.f - t) * (1.f - p);
    float a_t = t * 0.25f + (1.f - t) * 0.75f;
    float om = 1.f - p_t;
    return a_t * om * om * bce;
}

// ---------- kernel 1: stream blocks (0..2239, 7-deep NT) + hit blocks ----------
// Depth/blocks sweep: (980,16)=25.9, (1960,8)=22.4, (3136,5)=25.6 us.
// This probes the midpoint (2240,7) of the bracketed optimum.
// Hit: per-box-parallel winner via LDS u64 atomicMax (validated R12-R18).

__global__ __launch_bounds__(BLK) void fused_kernel(const float* __restrict__ pred,
                                                    const float* __restrict__ tgt,
                                                    float* __restrict__ partial) {
    __shared__ int      s_cell[NBOX];
    __shared__ float4   s_box[NBOX];
    __shared__ unsigned s_cbit[NBOX];
    __shared__ ull      s_key[NBOX];
    __shared__ unsigned s_mask[NBOX];
    __shared__ float    sred[BLK / 64];

    const int bid = blockIdx.x, tid = threadIdx.x;
    float acc = 0.f;

    if (bid < SGRID_B) {
        // ================= streaming path (non-temporal, 7-deep) =================
        const vf4* base = (const vf4*)pred + (size_t)bid * BREGION + tid;

        vf4 v0 = __builtin_nontemporal_load(base);
        vf4 v1 = __builtin_nontemporal_load(base + BLK);
        vf4 v2 = __builtin_nontemporal_load(base + 2 * BLK);
        vf4 v3 = __builtin_nontemporal_load(base + 3 * BLK);
        vf4 v4 = __builtin_nontemporal_load(base + 4 * BLK);
        vf4 v5 = __builtin_nontemporal_load(base + 5 * BLK);
        vf4 v6 = __builtin_nontemporal_load(base + 6 * BLK);

        // slot of float4 idx within cell = idx % 5; conf0=slot1.x, conf1=slot2.y
        // idx_j = bid*1792 + tid + j*256; 1792%5==2, 256%5==1
        float sacc = 0.f;
        int r = (bid * 2 + tid) % 5;
#define ACC(v) { if (r == 1) sacc += v.x * v.x; if (r == 2) sacc += v.y * v.y; \
                 ++r; if (r >= 5) r = 0; }
        ACC(v0) ACC(v1) ACC(v2) ACC(v3) ACC(v4) ACC(v5) ACC(v6)
#undef ACC
        acc = 0.1f * sacc;
    } else {
        // ================= hit path (one block per image) =================
        const int img = bid - HIT_BASE;

        if (tid < NBOX) {
            const float* t = tgt + ((size_t)img * NBOX + tid) * 5;
            float t0 = t[0], cx = t[1], cy = t[2], w = t[3], h = t[4];
            int cellid = -1; unsigned cb = 0u;
            if (t0 >= 0.f) {
                int cls = min(max((int)t0, 0), 9);
                int col = min(max((int)(cx * (float)S_GRID), 0), S_GRID - 1);
                int row = min(max((int)(cy * (float)S_GRID), 0), S_GRID - 1);
                cellid = row * S_GRID + col;
                cb = 1u << cls;
            }
            s_cell[tid] = cellid;
            s_box[tid]  = make_float4(cx, cy, w, h);
            s_cbit[tid] = cb;
            s_key[tid]  = 0ull;
            s_mask[tid] = 0u;
        }
        __syncthreads();

        int mycell = (tid < NBOX) ? s_cell[tid] : -1;
        int owner = tid;
        float4 pa, pb; float pc8 = 0.f, pc9 = 0.f;
        float colf = 0.f, rowf = 0.f;

        // step 1: per-box iou vs its own cell's two pred boxes
        if (mycell >= 0) {
            for (int j = 0; j < tid; ++j)
                if (s_cell[j] == mycell) { owner = j; break; }
            colf = (float)(mycell % S_GRID);
            rowf = (float)(mycell / S_GRID);
            const float* P = pred + ((size_t)img * SS + mycell) * 20;
            pa  = *(const float4*)P;        // p0 p1 p2 p3
            pb  = *(const float4*)(P + 4);  // conf0 p5 p6 p7
            pc8 = P[8]; pc9 = P[9];         // p8, conf1
            float4 g = s_box[tid];
            float dx0 = (pa.x + colf) * CELLSZ, dy0 = (pa.y + rowf) * CELLSZ;
            float i0 = iou_fn(dx0, dy0, pa.z, pa.w, g.x, g.y, g.z, g.w);
            float dx1 = (pb.y + colf) * CELLSZ, dy1 = (pb.z + rowf) * CELLSZ;
            float i1 = iou_fn(dx1, dy1, pb.w, pc8, g.x, g.y, g.z, g.w);
            float b = fmaxf(i0, i1);
            int bj = (i0 >= i1) ? 0 : 1;
            ull key = ((ull)__float_as_uint(b) << 32)
                    | (ull)((((unsigned)(NBOX - tid)) << 1) | (unsigned)bj);
            atomicMax(&s_key[owner], key);
            atomicOr(&s_mask[owner], s_cbit[tid]);
        }
        __syncthreads();

        // step 2: cell representatives compute the per-cell loss
        if (mycell >= 0 && owner == tid) {
            ull key = s_key[tid];
            float best_iou = __uint_as_float((unsigned)(key >> 32));
            unsigned lo = (unsigned)key;
            int bjw = (int)(lo & 1u);
            int m   = NBOX - (int)(lo >> 1);
            float4 g = s_box[m];
            unsigned mask = s_mask[tid];

            float conf0 = pb.x, conf1 = pc9;
            float rx = bjw ? pb.y : pa.x;
            float ry = bjw ? pb.z : pa.y;
            float rw = bjw ? pb.w : pa.z;
            float rh = bjw ? pc8  : pa.w;
            float rconf = bjw ? conf1 : conf0;
            float oconf = bjw ? conf0 : conf1;

            float pax = (rx + colf) * CELLSZ, pay = (ry + rowf) * CELLSZ;
            float paw = fabsf(rw), pah = fabsf(rh);
            float cx_rel = g.x * (float)S_GRID - colf;
            float cy_rel = g.y * (float)S_GRID - rowf;
            float gax = (cx_rel + colf) * CELLSZ;
            float gay = (cy_rel + rowf) * CELLSZ;
            float lcoord = ciou_fn(pax, pay, paw, pah, gax, gay, g.z, g.w);

            float dobj = rconf - best_iou;

            const float* P = pred + ((size_t)img * SS + mycell) * 20;
            float lcls = 0.f;
#pragma unroll
            for (int k = 0; k < 10; ++k) {
                float tk = (mask >> k) & 1u ? 1.f : 0.f;
                lcls += focal_fn(P[10 + k], tk);
            }

            acc = 5.f * lcoord + dobj * dobj + 0.1f * (oconf * oconf) + lcls
                - 0.1f * (conf0 * conf0 + conf1 * conf1);   // undo stream over-count
        }
    }

    // ---- block reduce -> partial (both paths) ----
    for (int off = 32; off > 0; off >>= 1) acc += __shfl_down(acc, off);
    int lane = tid & 63, wid = tid >> 6;
    if (lane == 0) sred[wid] = acc;
    __syncthreads();
    if (tid == 0) {
        float s = 0.f;
#pragma unroll
        for (int w = 0; w < BLK / 64; ++w) s += sred[w];
        partial[bid] = s;
    }
}

// ---------- kernel 2: final reduction (fixed order, deterministic) ----------

__global__ __launch_bounds__(BLK) void reduce_kernel(const float* __restrict__ partial,
                                                     float* __restrict__ out) {
    float acc = 0.f;
#pragma unroll
    for (int j = 0; j < (NPART + BLK - 1) / BLK; ++j) {   // ascending, bounds-checked
        int i = threadIdx.x + j * BLK;
        if (i < NPART) acc += partial[i];
    }
    for (int off = 32; off > 0; off >>= 1) acc += __shfl_down(acc, off);
    __shared__ float sred[BLK / 64];
    int lane = threadIdx.x & 63, wid = threadIdx.x >> 6;
    if (lane == 0) sred[wid] = acc;
    __syncthreads();
    if (threadIdx.x == 0) {
        float s = 0.f;
#pragma unroll
        for (int w = 0; w < BLK / 64; ++w) s += sred[w];
        out[0] = s / (float)BATCH_N;
    }
}

// ---------- launcher: TWO launches ----------

extern "C" void kernel_launch(void* const* d_in, const int* in_sizes, int n_in,
                              void* d_out, int out_size, void* d_ws, size_t ws_size,
                              hipStream_t stream) {
    const float* pred = (const float*)d_in[0];
    const float* tgt  = (const float*)d_in[1];
    float* partial = (float*)d_ws;   // NPART floats, fully rewritten every call

    fused_kernel<<<NPART, BLK, 0, stream>>>(pred, tgt, partial);
    reduce_kernel<<<1, BLK, 0, stream>>>(partial, (float*)d_out);
}

// Round 20
// 21.890 us; speedup vs baseline: 1.1940x; 1.1940x over previous
//
#include <hip/hip_runtime.h>
#include <math.h>

typedef unsigned long long ull;
typedef float vf4 __attribute__((ext_vector_type(4)));   // native vec for NT loads

#define S_GRID   112
#define BATCH_N  64
#define NBOX     100
#define SS       (S_GRID * S_GRID)       // 12544 cells per image
#define NCELLS   (BATCH_N * SS)          // 802816
#define NF4      (NCELLS * 5)            // 4,014,080 float4s in pred
#define CELLSZ   (1.0f / (float)S_GRID)
#define BLK      256
#define CH       8                       // float4 chunks per thread
#define SGRID_B  1960                    // 1960*256*8 == NF4 exactly (no tail)
#define HIT_BASE SGRID_B                 // hit blocks: 1960..2023
#define NPART    (SGRID_B + BATCH_N)     // 2024 partials
#define BREGION  (BLK * CH)              // 2048 float4s = 32KB contiguous per block

// ---------- device helpers ----------

__device__ __forceinline__ float iou_fn(float px, float py, float pw, float ph,
                                        float gx, float gy, float gw, float gh) {
    // matches reference _iou (eps = 1e-6)
    float px1 = px - pw * 0.5f, px2 = px + pw * 0.5f;
    float py1 = py - ph * 0.5f, py2 = py + ph * 0.5f;
    float gx1 = gx - gw * 0.5f, gx2 = gx + gw * 0.5f;
    float gy1 = gy - gh * 0.5f, gy2 = gy + gh * 0.5f;
    float iw = fmaxf(fminf(px2, gx2) - fmaxf(px1, gx1), 0.f);
    float ih = fmaxf(fminf(py2, gy2) - fmaxf(py1, gy1), 0.f);
    float inter = iw * ih;
    float ap = fmaxf(px2 - px1, 0.f) * fmaxf(py2 - py1, 0.f);
    float ag = fmaxf(gx2 - gx1, 0.f) * fmaxf(gy2 - gy1, 0.f);
    float uni = ap + ag - inter;
    return inter / (uni + 1e-6f);
}

__device__ __forceinline__ float ciou_fn(float px, float py, float pw, float ph,
                                         float gx, float gy, float gw, float gh) {
    // matches reference _ciou (eps = 1e-7)
    const float eps = 1e-7f;
    float px1 = px - pw * 0.5f, px2 = px + pw * 0.5f;
    float py1 = py - ph * 0.5f, py2 = py + ph * 0.5f;
    float gx1 = gx - gw * 0.5f, gx2 = gx + gw * 0.5f;
    float gy1 = gy - gh * 0.5f, gy2 = gy + gh * 0.5f;
    float iw = fmaxf(fminf(px2, gx2) - fmaxf(px1, gx1), 0.f);
    float ih = fmaxf(fminf(py2, gy2) - fmaxf(py1, gy1), 0.f);
    float inter = iw * ih;
    float ap = fmaxf(px2 - px1, 0.f) * fmaxf(py2 - py1, 0.f);
    float ag = fmaxf(gx2 - gx1, 0.f) * fmaxf(gy2 - gy1, 0.f);
    float uni = ap + ag - inter;
    float iou = inter / (uni + eps);
    float dx = px - gx, dy = py - gy;
    float rho2 = dx * dx + dy * dy;
    float cw = fmaxf(px2, gx2) - fminf(px1, gx1);
    float ch = fmaxf(py2, gy2) - fminf(py1, gy1);
    float c2 = cw * cw + ch * ch + eps;
    float dv = atanf(gw / (gh + eps)) - atanf(pw / (ph + eps));
    float v = 0.40528473456935109f * dv * dv;   // 4/pi^2
    float alpha = v / (1.f - iou + v + eps);
    return 1.f - iou + rho2 / c2 + alpha * v;
}

__device__ __forceinline__ float focal_fn(float logit, float t) {
    float bce = fmaxf(logit, 0.f) - logit * t + log1pf(expf(-fabsf(logit)));
    float p = 1.f / (1.f + expf(-logit));
    float p_t = t * p + (1.f - t) * (1.f - p);
    float a_t = t * 0.25f + (1.f - t) * 0.75f;
    float om = 1.f - p_t;
    return a_t * om * om * bce;
}

// ---------- kernel 1: stream blocks (0..1959, 8-deep NT) + hit blocks ----------
// EXACT REVERT TO R16 (22.4us) — the measured optimum of the blocks x depth
// sweep: (980,16)=25.9, (1960,8)=22.4, (2240,7)=26.1, (3136,5)=25.6.
// Stream: 32KB contiguous region per block, 8 NAMED independent NT float4
//         loads in flight (NT bypasses L2 retention: proved 29.1->22.4us).
// Hit: per-box-parallel winner via LDS u64 atomicMax (validated R12-R19).

__global__ __launch_bounds__(BLK) void fused_kernel(const float* __restrict__ pred,
                                                    const float* __restrict__ tgt,
                                                    float* __restrict__ partial) {
    __shared__ int      s_cell[NBOX];
    __shared__ float4   s_box[NBOX];
    __shared__ unsigned s_cbit[NBOX];
    __shared__ ull      s_key[NBOX];
    __shared__ unsigned s_mask[NBOX];
    __shared__ float    sred[BLK / 64];

    const int bid = blockIdx.x, tid = threadIdx.x;
    float acc = 0.f;

    if (bid < SGRID_B) {
        // ================= streaming path (non-temporal) =================
        const vf4* base = (const vf4*)pred + (size_t)bid * BREGION + tid;

        vf4 v0 = __builtin_nontemporal_load(base);
        vf4 v1 = __builtin_nontemporal_load(base + BLK);
        vf4 v2 = __builtin_nontemporal_load(base + 2 * BLK);
        vf4 v3 = __builtin_nontemporal_load(base + 3 * BLK);
        vf4 v4 = __builtin_nontemporal_load(base + 4 * BLK);
        vf4 v5 = __builtin_nontemporal_load(base + 5 * BLK);
        vf4 v6 = __builtin_nontemporal_load(base + 6 * BLK);
        vf4 v7 = __builtin_nontemporal_load(base + 7 * BLK);

        // slot of float4 idx within cell = idx % 5; conf0=slot1.x, conf1=slot2.y
        // idx_j = bid*2048 + tid + j*256; 256 % 5 == 1 -> r advances by 1
        float sacc = 0.f;
        int r = (bid * BREGION + tid) % 5;
#define ACC(v) { if (r == 1) sacc += v.x * v.x; if (r == 2) sacc += v.y * v.y; \
                 ++r; if (r >= 5) r = 0; }
        ACC(v0) ACC(v1) ACC(v2) ACC(v3) ACC(v4) ACC(v5) ACC(v6) ACC(v7)
#undef ACC
        acc = 0.1f * sacc;
    } else {
        // ================= hit path (one block per image) =================
        const int img = bid - HIT_BASE;

        if (tid < NBOX) {
            const float* t = tgt + ((size_t)img * NBOX + tid) * 5;
            float t0 = t[0], cx = t[1], cy = t[2], w = t[3], h = t[4];
            int cellid = -1; unsigned cb = 0u;
            if (t0 >= 0.f) {
                int cls = min(max((int)t0, 0), 9);
                int col = min(max((int)(cx * (float)S_GRID), 0), S_GRID - 1);
                int row = min(max((int)(cy * (float)S_GRID), 0), S_GRID - 1);
                cellid = row * S_GRID + col;
                cb = 1u << cls;
            }
            s_cell[tid] = cellid;
            s_box[tid]  = make_float4(cx, cy, w, h);
            s_cbit[tid] = cb;
            s_key[tid]  = 0ull;
            s_mask[tid] = 0u;
        }
        __syncthreads();

        int mycell = (tid < NBOX) ? s_cell[tid] : -1;
        int owner = tid;
        float4 pa, pb; float pc8 = 0.f, pc9 = 0.f;
        float colf = 0.f, rowf = 0.f;

        // step 1: per-box iou vs its own cell's two pred boxes
        if (mycell >= 0) {
            for (int j = 0; j < tid; ++j)
                if (s_cell[j] == mycell) { owner = j; break; }
            colf = (float)(mycell % S_GRID);
            rowf = (float)(mycell / S_GRID);
            const float* P = pred + ((size_t)img * SS + mycell) * 20;
            pa  = *(const float4*)P;        // p0 p1 p2 p3
            pb  = *(const float4*)(P + 4);  // conf0 p5 p6 p7
            pc8 = P[8]; pc9 = P[9];         // p8, conf1
            float4 g = s_box[tid];
            float dx0 = (pa.x + colf) * CELLSZ, dy0 = (pa.y + rowf) * CELLSZ;
            float i0 = iou_fn(dx0, dy0, pa.z, pa.w, g.x, g.y, g.z, g.w);
            float dx1 = (pb.y + colf) * CELLSZ, dy1 = (pb.z + rowf) * CELLSZ;
            float i1 = iou_fn(dx1, dy1, pb.w, pc8, g.x, g.y, g.z, g.w);
            float b = fmaxf(i0, i1);
            int bj = (i0 >= i1) ? 0 : 1;
            ull key = ((ull)__float_as_uint(b) << 32)
                    | (ull)((((unsigned)(NBOX - tid)) << 1) | (unsigned)bj);
            atomicMax(&s_key[owner], key);
            atomicOr(&s_mask[owner], s_cbit[tid]);
        }
        __syncthreads();

        // step 2: cell representatives compute the per-cell loss
        if (mycell >= 0 && owner == tid) {
            ull key = s_key[tid];
            float best_iou = __uint_as_float((unsigned)(key >> 32));
            unsigned lo = (unsigned)key;
            int bjw = (int)(lo & 1u);
            int m   = NBOX - (int)(lo >> 1);
            float4 g = s_box[m];
            unsigned mask = s_mask[tid];

            float conf0 = pb.x, conf1 = pc9;
            float rx = bjw ? pb.y : pa.x;
            float ry = bjw ? pb.z : pa.y;
            float rw = bjw ? pb.w : pa.z;
            float rh = bjw ? pc8  : pa.w;
            float rconf = bjw ? conf1 : conf0;
            float oconf = bjw ? conf0 : conf1;

            float pax = (rx + colf) * CELLSZ, pay = (ry + rowf) * CELLSZ;
            float paw = fabsf(rw), pah = fabsf(rh);
            float cx_rel = g.x * (float)S_GRID - colf;
            float cy_rel = g.y * (float)S_GRID - rowf;
            float gax = (cx_rel + colf) * CELLSZ;
            float gay = (cy_rel + rowf) * CELLSZ;
            float lcoord = ciou_fn(pax, pay, paw, pah, gax, gay, g.z, g.w);

            float dobj = rconf - best_iou;

            const float* P = pred + ((size_t)img * SS + mycell) * 20;
            float lcls = 0.f;
#pragma unroll
            for (int k = 0; k < 10; ++k) {
                float tk = (mask >> k) & 1u ? 1.f : 0.f;
                lcls += focal_fn(P[10 + k], tk);
            }

            acc = 5.f * lcoord + dobj * dobj + 0.1f * (oconf * oconf) + lcls
                - 0.1f * (conf0 * conf0 + conf1 * conf1);   // undo stream over-count
        }
    }

    // ---- block reduce -> partial (both paths) ----
    for (int off = 32; off > 0; off >>= 1) acc += __shfl_down(acc, off);
    int lane = tid & 63, wid = tid >> 6;
    if (lane == 0) sred[wid] = acc;
    __syncthreads();
    if (tid == 0) {
        float s = 0.f;
#pragma unroll
        for (int w = 0; w < BLK / 64; ++w) s += sred[w];
        partial[bid] = s;
    }
}

// ---------- kernel 2: final reduction (fixed order, deterministic) ----------

__global__ __launch_bounds__(BLK) void reduce_kernel(const float* __restrict__ partial,
                                                     float* __restrict__ out) {
    float acc = 0.f;
#pragma unroll
    for (int j = 0; j < (NPART + BLK - 1) / BLK; ++j) {   // ascending, bounds-checked
        int i = threadIdx.x + j * BLK;
        if (i < NPART) acc += partial[i];
    }
    for (int off = 32; off > 0; off >>= 1) acc += __shfl_down(acc, off);
    __shared__ float sred[BLK / 64];
    int lane = threadIdx.x & 63, wid = threadIdx.x >> 6;
    if (lane == 0) sred[wid] = acc;
    __syncthreads();
    if (threadIdx.x == 0) {
        float s = 0.f;
#pragma unroll
        for (int w = 0; w < BLK / 64; ++w) s += sred[w];
        out[0] = s / (float)BATCH_N;
    }
}

// ---------- launcher: TWO launches ----------

extern "C" void kernel_launch(void* const* d_in, const int* in_sizes, int n_in,
                              void* d_out, int out_size, void* d_ws, size_t ws_size,
                              hipStream_t stream) {
    const float* pred = (const float*)d_in[0];
    const float* tgt  = (const float*)d_in[1];
    float* partial = (float*)d_ws;   // NPART floats, fully rewritten every call

    fused_kernel<<<NPART, BLK, 0, stream>>>(pred, tgt, partial);
    reduce_kernel<<<1, BLK, 0, stream>>>(partial, (float*)d_out);
}